// Round 1
// baseline (111.789 us; speedup 1.0000x reference)
//
#include <hip/hip_runtime.h>
#include <math.h>

#define B_ 32
#define N_ 4096
#define D_ 1024
#define ROWS (B_ * N_)   // 131072 rows of x_full

// ---------------------------------------------------------------------------
// Mask dtype sniffing: jnp bool may arrive as 1-byte bools or as int32.
// If the first 64 u32 words are all 0/1 -> int32 layout (flag=1).
// All-true byte bools read as 0x01010101 -> byte layout (flag=0).
// Deterministic: pure function of input bytes.
// ---------------------------------------------------------------------------
__global__ void detect_mask_kernel(const unsigned* __restrict__ mask_u32,
                                   int* __restrict__ flag) {
    int ok = 1;
    for (int i = 0; i < 64; ++i) {
        if (mask_u32[i] > 1u) { ok = 0; break; }
    }
    *flag = ok;
}

// ---------------------------------------------------------------------------
// Pass 1: per row (b,n) compute logits = x·q * (1/32) (masked) and t = x·w.
// One wave per row; float4 coalesced loads; q/w fragments hoisted to regs.
// ---------------------------------------------------------------------------
__global__ __launch_bounds__(256) void probe_pass1(
    const float* __restrict__ x,          // [B*N, D]
    const float* __restrict__ q,          // [D]
    const float* __restrict__ w,          // [D]
    const unsigned char* __restrict__ mask_b,
    const unsigned* __restrict__ mask_i,
    const int* __restrict__ flag,
    float* __restrict__ logits,           // [B*N]
    float* __restrict__ tvals)            // [B*N]
{
    const int lane   = threadIdx.x & 63;
    const int gwave  = (int)((blockIdx.x * blockDim.x + threadIdx.x) >> 6);
    const int nwaves = (int)((gridDim.x * blockDim.x) >> 6);

    // Hoist this lane's q/w fragments (16 floats each) into registers.
    const float4* q4 = (const float4*)q;
    const float4* w4 = (const float4*)w;
    float4 qv[4], wv[4];
#pragma unroll
    for (int j = 0; j < 4; ++j) {
        qv[j] = q4[j * 64 + lane];
        wv[j] = w4[j * 64 + lane];
    }

    const int use_i32 = *flag;

    for (int row = gwave; row < ROWS; row += nwaves) {
        const float4* xr = (const float4*)(x + (size_t)row * D_);
        float aq = 0.f, aw = 0.f;
#pragma unroll
        for (int j = 0; j < 4; ++j) {
            float4 xv = xr[j * 64 + lane];   // lanes consecutive -> 1 KiB coalesced
            aq += xv.x * qv[j].x + xv.y * qv[j].y + xv.z * qv[j].z + xv.w * qv[j].w;
            aw += xv.x * wv[j].x + xv.y * wv[j].y + xv.z * wv[j].z + xv.w * wv[j].w;
        }
#pragma unroll
        for (int off = 32; off; off >>= 1) {
            aq += __shfl_xor(aq, off);
            aw += __shfl_xor(aw, off);
        }
        if (lane == 0) {
            bool m = use_i32 ? (mask_i[row] != 0u) : (mask_b[row] != 0);
            logits[row] = m ? aq * 0.03125f : -INFINITY;   // 1/sqrt(1024) = 1/32
            tvals[row]  = aw;
        }
    }
}

// ---------------------------------------------------------------------------
// Pass 2: per batch b, softmax over N=4096 logits; write alpha and
// scores[b] = (sum e*t)/(sum e) + head_b.
// 32 blocks x 256 threads; 16 elements (4x float4) per thread.
// ---------------------------------------------------------------------------
__global__ __launch_bounds__(256) void probe_pass2(
    const float* __restrict__ logits,     // [B, N]
    const float* __restrict__ tvals,      // [B, N]
    const float* __restrict__ head_b,     // [1]
    float* __restrict__ out)              // [0..B): scores, [B..B+B*N): alpha
{
    const int b    = blockIdx.x;
    const int tid  = threadIdx.x;
    const int lane = tid & 63;
    const int wid  = tid >> 6;

    __shared__ float redmax[4];
    __shared__ float redsum[8];

    const float4* l4 = (const float4*)(logits + (size_t)b * N_);
    const float4* t4 = (const float4*)(tvals  + (size_t)b * N_);

    float4 lv[4], tv[4];
#pragma unroll
    for (int k = 0; k < 4; ++k) {
        lv[k] = l4[k * 256 + tid];
        tv[k] = t4[k * 256 + tid];
    }

    // ---- block max ----
    float m = -INFINITY;
#pragma unroll
    for (int k = 0; k < 4; ++k)
        m = fmaxf(m, fmaxf(fmaxf(lv[k].x, lv[k].y), fmaxf(lv[k].z, lv[k].w)));
#pragma unroll
    for (int off = 32; off; off >>= 1) m = fmaxf(m, __shfl_xor(m, off));
    if (lane == 0) redmax[wid] = m;
    __syncthreads();
    m = fmaxf(fmaxf(redmax[0], redmax[1]), fmaxf(redmax[2], redmax[3]));

    // ---- exp + partial sums ----
    float se = 0.f, set = 0.f;
    float4 ev[4];
#pragma unroll
    for (int k = 0; k < 4; ++k) {
        ev[k].x = __expf(lv[k].x - m);
        ev[k].y = __expf(lv[k].y - m);
        ev[k].z = __expf(lv[k].z - m);
        ev[k].w = __expf(lv[k].w - m);
        se  += ev[k].x + ev[k].y + ev[k].z + ev[k].w;
        set += ev[k].x * tv[k].x + ev[k].y * tv[k].y
             + ev[k].z * tv[k].z + ev[k].w * tv[k].w;
    }
#pragma unroll
    for (int off = 32; off; off >>= 1) {
        se  += __shfl_xor(se, off);
        set += __shfl_xor(set, off);
    }
    if (lane == 0) { redsum[wid] = se; redsum[4 + wid] = set; }
    __syncthreads();
    se  = redsum[0] + redsum[1] + redsum[2] + redsum[3];
    set = redsum[4] + redsum[5] + redsum[6] + redsum[7];

    const float inv = 1.0f / se;

    // ---- write alpha (offset by B scores at the front of d_out) ----
    float4* a4 = (float4*)(out + B_ + (size_t)b * N_);
#pragma unroll
    for (int k = 0; k < 4; ++k) {
        float4 a;
        a.x = ev[k].x * inv; a.y = ev[k].y * inv;
        a.z = ev[k].z * inv; a.w = ev[k].w * inv;
        a4[k * 256 + tid] = a;
    }

    if (tid == 0) out[b] = set * inv + head_b[0];
}

// ---------------------------------------------------------------------------
extern "C" void kernel_launch(void* const* d_in, const int* in_sizes, int n_in,
                              void* d_out, int out_size, void* d_ws, size_t ws_size,
                              hipStream_t stream) {
    // setup_inputs order: x_final, x_full, mask, q, head_w, head_b
    const float* x_full = (const float*)d_in[1];
    const void*  mask   = d_in[2];
    const float* q      = (const float*)d_in[3];
    const float* head_w = (const float*)d_in[4];
    const float* head_b = (const float*)d_in[5];
    float* out = (float*)d_out;

    // workspace layout: logits [ROWS] f32 | tvals [ROWS] f32 | flag int
    float* logits = (float*)d_ws;
    float* tvals  = logits + ROWS;
    int*   flag   = (int*)(tvals + ROWS);

    detect_mask_kernel<<<1, 1, 0, stream>>>((const unsigned*)mask, flag);

    // 2048 blocks x 4 waves = 8192 waves (full machine), 16 rows per wave.
    probe_pass1<<<2048, 256, 0, stream>>>(
        x_full, q, head_w,
        (const unsigned char*)mask, (const unsigned*)mask, flag,
        logits, tvals);

    probe_pass2<<<B_, 256, 0, stream>>>(logits, tvals, head_b, out);
}

// Round 2
// 88.559 us; speedup vs baseline: 1.2623x; 1.2623x over previous
//
#include <hip/hip_runtime.h>
#include <math.h>

#define B_ 32
#define N_ 4096
#define D_ 1024
#define ROWS (B_ * N_)        // 131072 rows of x_full

#define P1_BLOCKS 2048
#define P1_THREADS 256
#define NWAVES (P1_BLOCKS * (P1_THREADS / 64))   // 8192 waves
#define ROWS_PER_WAVE (ROWS / NWAVES)            // 16

typedef float f32x4 __attribute__((ext_vector_type(4)));

// ---------------------------------------------------------------------------
// Pass 1: per row (b,n): logits = x·q/32 (masked), t = x·w.
// One wave per 16 CONTIGUOUS rows; float4 coalesced nontemporal loads;
// q/w fragments in registers; result of row i parked in lane i, then one
// coalesced 16-lane store. Mask layout (byte-bool vs int32) sniffed inline:
// all-true byte mask reads as 0x01010101 (>1) -> byte mode; int32 0/1 -> i32.
// ---------------------------------------------------------------------------
__global__ __launch_bounds__(256) void probe_pass1(
    const float* __restrict__ x,            // [B*N, D]
    const float* __restrict__ q,            // [D]
    const float* __restrict__ w,            // [D]
    const unsigned char* __restrict__ mask_b,
    const unsigned* __restrict__ mask_i,
    float* __restrict__ logits,             // [B*N]
    float* __restrict__ tvals)              // [B*N]
{
    const int lane  = threadIdx.x & 63;
    const int gwave = (int)((blockIdx.x * blockDim.x + threadIdx.x) >> 6);
    const int base  = gwave * ROWS_PER_WAVE;

    // Inline mask-layout sniff: uniform across the wave, reads 64 L2-hot words.
    const bool use_i32 = (__ballot(mask_i[lane] <= 1u) == ~0ull);

    // Hoist this lane's q/w fragments (16 floats each) into registers.
    const f32x4* q4 = (const f32x4*)q;
    const f32x4* w4 = (const f32x4*)w;
    f32x4 qv[4], wv[4];
#pragma unroll
    for (int j = 0; j < 4; ++j) {
        qv[j] = q4[j * 64 + lane];
        wv[j] = w4[j * 64 + lane];
    }

    float lq = 0.f, lw = 0.f;   // lane i ends up holding row (base+i)'s results

#pragma unroll 4
    for (int i = 0; i < ROWS_PER_WAVE; ++i) {
        const f32x4* xr = (const f32x4*)(x + (size_t)(base + i) * D_);
        f32x4 xv[4];
#pragma unroll
        for (int j = 0; j < 4; ++j)
            xv[j] = __builtin_nontemporal_load(&xr[j * 64 + lane]);

        float aq = 0.f, aw = 0.f;
#pragma unroll
        for (int j = 0; j < 4; ++j) {
            aq += xv[j].x * qv[j].x + xv[j].y * qv[j].y
                + xv[j].z * qv[j].z + xv[j].w * qv[j].w;
            aw += xv[j].x * wv[j].x + xv[j].y * wv[j].y
                + xv[j].z * wv[j].z + xv[j].w * wv[j].w;
        }
#pragma unroll
        for (int off = 32; off; off >>= 1) {
            aq += __shfl_xor(aq, off);
            aw += __shfl_xor(aw, off);
        }
        if (lane == i) { lq = aq; lw = aw; }   // broadcast result -> park in lane i
    }

    if (lane < ROWS_PER_WAVE) {
        const int row = base + lane;
        const bool m = use_i32 ? (mask_i[row] != 0u) : (mask_b[row] != 0);
        logits[row] = m ? lq * 0.03125f : -INFINITY;   // 1/sqrt(1024) = 1/32
        tvals[row]  = lw;
    }
}

// ---------------------------------------------------------------------------
// Pass 2: per batch b, softmax over N=4096 logits; write alpha and
// scores[b] = (sum e*t)/(sum e) + head_b.  32 blocks x 256 threads.
// ---------------------------------------------------------------------------
__global__ __launch_bounds__(256) void probe_pass2(
    const float* __restrict__ logits,       // [B, N]
    const float* __restrict__ tvals,        // [B, N]
    const float* __restrict__ head_b,       // [1]
    float* __restrict__ out)                // [0..B): scores, [B..): alpha
{
    const int b    = blockIdx.x;
    const int tid  = threadIdx.x;
    const int lane = tid & 63;
    const int wid  = tid >> 6;

    __shared__ float redmax[4];
    __shared__ float redsum[8];

    const float4* l4 = (const float4*)(logits + (size_t)b * N_);
    const float4* t4 = (const float4*)(tvals  + (size_t)b * N_);

    float4 lv[4], tv[4];
#pragma unroll
    for (int k = 0; k < 4; ++k) {
        lv[k] = l4[k * 256 + tid];
        tv[k] = t4[k * 256 + tid];
    }

    // ---- block max ----
    float m = -INFINITY;
#pragma unroll
    for (int k = 0; k < 4; ++k)
        m = fmaxf(m, fmaxf(fmaxf(lv[k].x, lv[k].y), fmaxf(lv[k].z, lv[k].w)));
#pragma unroll
    for (int off = 32; off; off >>= 1) m = fmaxf(m, __shfl_xor(m, off));
    if (lane == 0) redmax[wid] = m;
    __syncthreads();
    m = fmaxf(fmaxf(redmax[0], redmax[1]), fmaxf(redmax[2], redmax[3]));

    // ---- exp + partial sums ----
    float se = 0.f, set = 0.f;
    float4 ev[4];
#pragma unroll
    for (int k = 0; k < 4; ++k) {
        ev[k].x = __expf(lv[k].x - m);
        ev[k].y = __expf(lv[k].y - m);
        ev[k].z = __expf(lv[k].z - m);
        ev[k].w = __expf(lv[k].w - m);
        se  += ev[k].x + ev[k].y + ev[k].z + ev[k].w;
        set += ev[k].x * tv[k].x + ev[k].y * tv[k].y
             + ev[k].z * tv[k].z + ev[k].w * tv[k].w;
    }
#pragma unroll
    for (int off = 32; off; off >>= 1) {
        se  += __shfl_xor(se, off);
        set += __shfl_xor(set, off);
    }
    if (lane == 0) { redsum[wid] = se; redsum[4 + wid] = set; }
    __syncthreads();
    se  = redsum[0] + redsum[1] + redsum[2] + redsum[3];
    set = redsum[4] + redsum[5] + redsum[6] + redsum[7];

    const float inv = 1.0f / se;

    // ---- write alpha (offset by B scores at the front of d_out) ----
    float4* a4 = (float4*)(out + B_ + (size_t)b * N_);
#pragma unroll
    for (int k = 0; k < 4; ++k) {
        float4 a;
        a.x = ev[k].x * inv; a.y = ev[k].y * inv;
        a.z = ev[k].z * inv; a.w = ev[k].w * inv;
        a4[k * 256 + tid] = a;
    }

    if (tid == 0) out[b] = set * inv + head_b[0];
}

// ---------------------------------------------------------------------------
extern "C" void kernel_launch(void* const* d_in, const int* in_sizes, int n_in,
                              void* d_out, int out_size, void* d_ws, size_t ws_size,
                              hipStream_t stream) {
    // setup_inputs order: x_final, x_full, mask, q, head_w, head_b
    const float* x_full = (const float*)d_in[1];
    const void*  mask   = d_in[2];
    const float* q      = (const float*)d_in[3];
    const float* head_w = (const float*)d_in[4];
    const float* head_b = (const float*)d_in[5];
    float* out = (float*)d_out;

    // workspace layout: logits [ROWS] f32 | tvals [ROWS] f32
    float* logits = (float*)d_ws;
    float* tvals  = logits + ROWS;

    probe_pass1<<<P1_BLOCKS, P1_THREADS, 0, stream>>>(
        x_full, q, head_w,
        (const unsigned char*)mask, (const unsigned*)mask,
        logits, tvals);

    probe_pass2<<<B_, 256, 0, stream>>>(logits, tvals, head_b, out);
}